// Round 11
// baseline (645.084 us; speedup 1.0000x reference)
//
#include <hip/hip_runtime.h>
#include <hip/hip_bf16.h>
#include <math.h>

#define D 2048
#define H 256
#define E 16
#define TMB 16                 // tokens per block
#define BK 16                  // k-chunk; each ku-lane owns a 4-k window
#define NCH (D / BK)           // 128
#define LDK 20                 // Wp LDS row stride (floats): uniform bank groups for b128
#define WP_OFF 0               // [256][20] = 5120 floats
#define X_OFF 5120             // [16][16]  = 256   (staging ends 5376)
#define SB_LDW 257
#define SB_OFF 0               // [16][257] = 4112 (aliases staging during post)
#define WG_OFF 5376            // [16][256] = 4096 (persistent)
#define LB_OFF 9472
#define Z_OFF  9488
#define SMEM_FLOATS 9504       // 38.0 KB -> 4 blocks/CU (LDS 152KB <= 160KB)
#define THREADS 256
#define WS_STRIDE 20

// 256-thr blocks: the only workgroup size where hipcc's VGPR heuristic behaved
// (R2:144, R6:68, never spilled) AND multi-block/CU residency worked (R6).
// arg2=4 -> 4 workgroups/CU target -> 128-VGPR cap (guide: for 256-thr blocks
// the 2nd launch_bounds arg equals workgroups/CU directly).
__global__ __launch_bounds__(THREADS, 4)
void router_main(const float* __restrict__ x, const float* __restrict__ Wp,
                 const float* __restrict__ Wg, const float* __restrict__ lnw_g,
                 const float* __restrict__ lnb_g, const float* __restrict__ temp_g,
                 float* __restrict__ out_rw, float* __restrict__ out_disp,
                 float* __restrict__ ws_part)
{
    __shared__ __align__(16) float smem[SMEM_FLOATS];
    const int t  = threadIdx.x;
    const int tx = t & 15;           // h-lane (lane bits 0-3)
    const int ku = (t >> 4) & 3;     // private 4-k window (lane bits 4-5)
    const int wv = t >> 6;           // wave 0..3
    const int tb = wv & 1;           // token octet
    const int hb = wv >> 1;          // h-half
    const int wrow = t >> 2;         // Wp staging row 0..63 (x4 passes)
    const int wcol = (t & 3) << 2;   // staging col (floats)
    const int tok0 = blockIdx.x * TMB;

    // stage Wg once into persistent region [5376, 9472)
    #pragma unroll
    for (int p = 0; p < 4; ++p)
        *(float4*)&smem[WG_OFF + (p * 256 + t) * 4] = *(const float4*)&Wg[(p * 256 + t) * 4];

    float acc[8][8];
    #pragma unroll
    for (int i = 0; i < 8; ++i)
        #pragma unroll
        for (int j = 0; j < 8; ++j) acc[i][j] = 0.f;

    float4 wst[4], xst;
    auto ISSUE = [&](int k0) {
        #pragma unroll
        for (int p = 0; p < 4; ++p)
            wst[p] = *(const float4*)&Wp[(size_t)(p * 64 + wrow) * D + k0 + wcol];
        if (t < 64) xst = *(const float4*)&x[(size_t)(tok0 + (t >> 2)) * D + k0 + wcol];
    };
    ISSUE(0);

    const float* wbase = &smem[WP_OFF + (hb * 128 + tx) * LDK + ku * 4];
    const float* xbase = &smem[X_OFF + tb * 128 + ku * 4];   // tb*8 tokens * 16 floats

    for (int c = 0; c < NCH; ++c) {
        __syncthreads();                     // prior chunk's LDS reads done
        #pragma unroll
        for (int p = 0; p < 4; ++p)
            *(float4*)&smem[WP_OFF + (p * 64 + wrow) * LDK + wcol] = wst[p];
        if (t < 64) *(float4*)&smem[X_OFF + (t >> 2) * 16 + wcol] = xst;
        __syncthreads();
        if (c + 1 < NCH) ISSUE((c + 1) * BK);   // prefetch under compute

        float4 xa[8];
        #pragma unroll
        for (int i = 0; i < 8; ++i)
            xa[i] = *(const float4*)&xbase[i * 16];          // 16-way broadcast reads
        #pragma unroll
        for (int j = 0; j < 8; ++j) {
            const float4 wvv = *(const float4*)&wbase[j * 16 * LDK];  // 64-distinct b128
            #pragma unroll
            for (int i = 0; i < 8; ++i) {
                acc[i][j] = fmaf(xa[i].x, wvv.x, acc[i][j]);
                acc[i][j] = fmaf(xa[i].y, wvv.y, acc[i][j]);
                acc[i][j] = fmaf(xa[i].z, wvv.z, acc[i][j]);
                acc[i][j] = fmaf(xa[i].w, wvv.w, acc[i][j]);
            }
        }
    }

    // ---- k-window reduction: in-wave butterflies over lane bits 4,5 ----
    #pragma unroll
    for (int i = 0; i < 8; ++i)
        #pragma unroll
        for (int j = 0; j < 8; ++j) {
            acc[i][j] += __shfl_xor(acc[i][j], 16);
            acc[i][j] += __shfl_xor(acc[i][j], 32);
        }

    __syncthreads();                          // staging region now dead

    // ---- dump proj into SB [16][257]; zero reducers ----
    if (ku == 0) {
        #pragma unroll
        for (int i = 0; i < 8; ++i)
            #pragma unroll
            for (int j = 0; j < 8; ++j)
                smem[SB_OFF + (tb * 8 + i) * SB_LDW + hb * 128 + tx + 16 * j] = acc[i][j];
    }
    if (t < 16)  smem[LB_OFF + t] = 0.f;
    if (t == 16) smem[Z_OFF] = 0.f;
    __syncthreads();

    // ---- post phase: one token per 16-thread slot (single pass) ----
    const int ptx  = t & 15;
    const int tokl = t >> 4;                  // 0..15
    const int tok  = tok0 + tokl;
    const float temp = fabsf(temp_g[0]) + 1e-6f;

    float lnw[16], lnb[16];
    #pragma unroll
    for (int j = 0; j < 16; ++j) {
        lnw[j] = lnw_g[ptx + 16 * j];
        lnb[j] = lnb_g[ptx + 16 * j];
    }

    float pr[16];
    #pragma unroll
    for (int j = 0; j < 16; ++j)
        pr[j] = smem[SB_OFF + tokl * SB_LDW + ptx + 16 * j];

    // mean / variance over H (16-lane butterfly)
    float s = 0.f;
    #pragma unroll
    for (int j = 0; j < 16; ++j) s += pr[j];
    s += __shfl_xor(s, 1); s += __shfl_xor(s, 2);
    s += __shfl_xor(s, 4); s += __shfl_xor(s, 8);
    const float mu = s * (1.f / 256.f);
    float v = 0.f;
    #pragma unroll
    for (int j = 0; j < 16; ++j) { const float d = pr[j] - mu; v = fmaf(d, d, v); }
    v += __shfl_xor(v, 1); v += __shfl_xor(v, 2);
    v += __shfl_xor(v, 4); v += __shfl_xor(v, 8);
    const float rstd = 1.0f / sqrtf(v * (1.f / 256.f) + 1e-5f);

    float n[16];
    #pragma unroll
    for (int j = 0; j < 16; ++j)
        n[j] = fmaf((pr[j] - mu) * rstd, lnw[j], lnb[j]);

    float p[16];
    #pragma unroll
    for (int e = 0; e < 16; ++e) p[e] = 0.f;
    #pragma unroll
    for (int j = 0; j < 16; ++j) {
        const float nv = n[j];
        const int  h   = ptx + 16 * j;
        #pragma unroll
        for (int e = 0; e < 16; ++e)
            p[e] = fmaf(nv, smem[WG_OFF + e * H + h], p[e]);
    }
    #pragma unroll
    for (int m = 1; m < 16; m <<= 1)
        #pragma unroll
        for (int e = 0; e < 16; ++e) p[e] += __shfl_xor(p[e], m);
    #pragma unroll
    for (int e = 0; e < 16; ++e) p[e] = p[e] / temp;

    float myz = 0.f;
    if (ptx == 0) {
        #pragma unroll
        for (int e = 0; e < 16; ++e) myz = fmaf(p[e], p[e], myz);
    }

    // softmax (stable)
    float mx = p[0];
    #pragma unroll
    for (int e = 1; e < 16; ++e) mx = fmaxf(mx, p[e]);
    float w[16]; float sw = 0.f;
    #pragma unroll
    for (int e = 0; e < 16; ++e) { w[e] = expf(p[e] - mx); sw += w[e]; }
    #pragma unroll
    for (int e = 0; e < 16; ++e) w[e] = w[e] / sw;

    // top-2 (ties -> lower index)
    float w1 = -1.f; int i1 = 0; float w2 = -1.f; int i2 = 0;
    #pragma unroll
    for (int e = 0; e < 16; ++e) {
        const float we = w[e];
        if (we > w1)      { w2 = w1; i2 = i1; w1 = we; i1 = e; }
        else if (we > w2) { w2 = we; i2 = e; }
    }
    const float rs = 1.f / (w1 + w2 + 1e-6f);
    out_rw  [(size_t)tok * E + ptx] = w[ptx];
    out_disp[(size_t)tok * E + ptx] = (ptx == i1) ? w1 * rs : (ptx == i2 ? w2 * rs : 0.f);

    // ---- loss partials: in-wave reduce 4 tokens, then LDS atomics ----
    float mylb = w[ptx];
    mylb += __shfl_xor(mylb, 16); mylb += __shfl_xor(mylb, 32);
    myz  += __shfl_xor(myz, 16);  myz  += __shfl_xor(myz, 32);
    if ((t & 63) < 16) atomicAdd(&smem[LB_OFF + ptx], mylb);
    if ((t & 63) == 0) atomicAdd(&smem[Z_OFF], myz);
    __syncthreads();
    if (t < 16)  ws_part[blockIdx.x * WS_STRIDE + t]  = smem[LB_OFF + t];
    if (t == 16) ws_part[blockIdx.x * WS_STRIDE + 16] = smem[Z_OFF];
}

__global__ void router_final(const float* __restrict__ ws_part,
                             float* __restrict__ out_loss, int nblocks, int T)
{
    const int l = threadIdx.x;   // 64 threads
    float lb[16]; float z = 0.f;
    #pragma unroll
    for (int e = 0; e < 16; ++e) lb[e] = 0.f;
    for (int b = l; b < nblocks; b += 64) {
        #pragma unroll
        for (int e = 0; e < 16; ++e) lb[e] += ws_part[b * WS_STRIDE + e];
        z += ws_part[b * WS_STRIDE + 16];
    }
    #pragma unroll
    for (int m = 1; m < 64; m <<= 1) {
        #pragma unroll
        for (int e = 0; e < 16; ++e) lb[e] += __shfl_xor(lb[e], m);
        z += __shfl_xor(z, m);
    }
    if (l == 0) {
        const float zloss = z / (float)(T * 16);
        const float ideal = 1.f / 16.f;
        float lbl = 0.f;
        #pragma unroll
        for (int e = 0; e < 16; ++e) {
            const float a = lb[e] / (float)T;
            lbl += ideal * (logf(ideal) - logf(a));
        }
        lbl *= (1.f / 16.f);
        out_loss[0] = 0.005f * zloss + 0.005f * lbl;
    }
}

extern "C" void kernel_launch(void* const* d_in, const int* in_sizes, int n_in,
                              void* d_out, int out_size, void* d_ws, size_t ws_size,
                              hipStream_t stream)
{
    const float* x    = (const float*)d_in[0];
    const float* Wp   = (const float*)d_in[1];
    const float* Wg   = (const float*)d_in[2];
    const float* lnw  = (const float*)d_in[3];
    const float* lnb  = (const float*)d_in[4];
    const float* temp = (const float*)d_in[5];
    const int T = in_sizes[0] / D;           // 16384
    float* out      = (float*)d_out;
    float* out_rw   = out;
    float* out_disp = out + (size_t)T * E;
    float* out_loss = out + (size_t)2 * T * E;
    float* ws_part  = (float*)d_ws;
    const int nblocks = T / TMB;             // 1024

    hipLaunchKernelGGL(router_main, dim3(nblocks), dim3(THREADS), 0, stream,
                       x, Wp, Wg, lnw, lnb, temp, out_rw, out_disp, ws_part);
    hipLaunchKernelGGL(router_final, dim3(1), dim3(64), 0, stream,
                       ws_part, out_loss, nblocks, T);
}

// Round 12
// 605.128 us; speedup vs baseline: 1.0660x; 1.0660x over previous
//
#include <hip/hip_runtime.h>
#include <hip/hip_bf16.h>
#include <math.h>

#define D 2048
#define H 256
#define E 16
#define TMB 16                 // tokens per block
#define BK 16                  // k-chunk; each ku-lane owns a 4-k window
#define NCH (D / BK)           // 128
#define LDK 20                 // Wp LDS row stride (floats): uniform bank groups for b128
#define WP_OFF 0               // [256][20] = 5120 floats
#define X_OFF 5120             // [16][16]  = 256   (staging ends 5376)
#define SB_LDW 257
#define SB_OFF 0               // [16][257] = 4112 (aliases staging during post)
#define WG_OFF 5376            // [16][256] = 4096 (persistent)
#define LB_OFF 9472
#define Z_OFF  9488
#define SMEM_FLOATS 9504       // 38.0 KB
#define THREADS 256
#define WS_STRIDE 20

// HARD-WON RULE (R5/R8/R9/R10/R11): on this toolchain ANY occupancy hint
// (__launch_bounds__ 2nd arg, amdgpu_waves_per_eu) collapses the VGPR cap to 64
// -> catastrophic scratch spill. Bare __launch_bounds__(N) lets the allocator
// choose (R2:144, R6:68, R7:80 - never spilled). DO NOT add a second argument.
__global__ __launch_bounds__(THREADS)
void router_main(const float* __restrict__ x, const float* __restrict__ Wp,
                 const float* __restrict__ Wg, const float* __restrict__ lnw_g,
                 const float* __restrict__ lnb_g, const float* __restrict__ temp_g,
                 float* __restrict__ out_rw, float* __restrict__ out_disp,
                 float* __restrict__ ws_part)
{
    __shared__ __align__(16) float smem[SMEM_FLOATS];
    const int t  = threadIdx.x;
    const int tx = t & 15;           // h-lane (lane bits 0-3)
    const int ku = (t >> 4) & 3;     // private 4-k window (lane bits 4-5)
    const int wv = t >> 6;           // wave 0..3
    const int tb = wv & 1;           // token octet
    const int hb = wv >> 1;          // h-half
    const int wrow = t >> 2;         // Wp staging row 0..63 (x4 passes)
    const int wcol = (t & 3) << 2;   // staging col (floats)
    const int tok0 = blockIdx.x * TMB;

    // stage Wg once into persistent region [5376, 9472)
    #pragma unroll
    for (int p = 0; p < 4; ++p)
        *(float4*)&smem[WG_OFF + (p * 256 + t) * 4] = *(const float4*)&Wg[(p * 256 + t) * 4];

    float acc[8][8];
    #pragma unroll
    for (int i = 0; i < 8; ++i)
        #pragma unroll
        for (int j = 0; j < 8; ++j) acc[i][j] = 0.f;

    float4 wst[4], xst;
    auto ISSUE = [&](int k0) {
        #pragma unroll
        for (int p = 0; p < 4; ++p)
            wst[p] = *(const float4*)&Wp[(size_t)(p * 64 + wrow) * D + k0 + wcol];
        if (t < 64) xst = *(const float4*)&x[(size_t)(tok0 + (t >> 2)) * D + k0 + wcol];
    };
    ISSUE(0);

    const float* wbase = &smem[WP_OFF + (hb * 128 + tx) * LDK + ku * 4];
    const float* xbase = &smem[X_OFF + tb * 128 + ku * 4];   // tb*8 tokens * 16 floats

    for (int c = 0; c < NCH; ++c) {
        __syncthreads();                     // prior chunk's LDS reads done
        #pragma unroll
        for (int p = 0; p < 4; ++p)
            *(float4*)&smem[WP_OFF + (p * 64 + wrow) * LDK + wcol] = wst[p];
        if (t < 64) *(float4*)&smem[X_OFF + (t >> 2) * 16 + wcol] = xst;
        __syncthreads();
        if (c + 1 < NCH) ISSUE((c + 1) * BK);   // prefetch under compute

        float4 xa[8];
        #pragma unroll
        for (int i = 0; i < 8; ++i)
            xa[i] = *(const float4*)&xbase[i * 16];          // 16-way broadcast reads
        #pragma unroll
        for (int j = 0; j < 8; ++j) {
            const float4 wvv = *(const float4*)&wbase[j * 16 * LDK];  // 64-distinct b128
            #pragma unroll
            for (int i = 0; i < 8; ++i) {
                acc[i][j] = fmaf(xa[i].x, wvv.x, acc[i][j]);
                acc[i][j] = fmaf(xa[i].y, wvv.y, acc[i][j]);
                acc[i][j] = fmaf(xa[i].z, wvv.z, acc[i][j]);
                acc[i][j] = fmaf(xa[i].w, wvv.w, acc[i][j]);
            }
        }
    }

    // ---- k-window reduction: in-wave butterflies over lane bits 4,5 ----
    #pragma unroll
    for (int i = 0; i < 8; ++i)
        #pragma unroll
        for (int j = 0; j < 8; ++j) {
            acc[i][j] += __shfl_xor(acc[i][j], 16);
            acc[i][j] += __shfl_xor(acc[i][j], 32);
        }

    __syncthreads();                          // staging region now dead

    // ---- dump proj into SB [16][257]; zero reducers ----
    if (ku == 0) {
        #pragma unroll
        for (int i = 0; i < 8; ++i)
            #pragma unroll
            for (int j = 0; j < 8; ++j)
                smem[SB_OFF + (tb * 8 + i) * SB_LDW + hb * 128 + tx + 16 * j] = acc[i][j];
    }
    if (t < 16)  smem[LB_OFF + t] = 0.f;
    if (t == 16) smem[Z_OFF] = 0.f;
    __syncthreads();

    // ---- post phase: one token per 16-thread slot (single pass) ----
    const int ptx  = t & 15;
    const int tokl = t >> 4;                  // 0..15
    const int tok  = tok0 + tokl;
    const float temp = fabsf(temp_g[0]) + 1e-6f;

    float lnw[16], lnb[16];
    #pragma unroll
    for (int j = 0; j < 16; ++j) {
        lnw[j] = lnw_g[ptx + 16 * j];
        lnb[j] = lnb_g[ptx + 16 * j];
    }

    float pr[16];
    #pragma unroll
    for (int j = 0; j < 16; ++j)
        pr[j] = smem[SB_OFF + tokl * SB_LDW + ptx + 16 * j];

    // mean / variance over H (16-lane butterfly)
    float s = 0.f;
    #pragma unroll
    for (int j = 0; j < 16; ++j) s += pr[j];
    s += __shfl_xor(s, 1); s += __shfl_xor(s, 2);
    s += __shfl_xor(s, 4); s += __shfl_xor(s, 8);
    const float mu = s * (1.f / 256.f);
    float v = 0.f;
    #pragma unroll
    for (int j = 0; j < 16; ++j) { const float d = pr[j] - mu; v = fmaf(d, d, v); }
    v += __shfl_xor(v, 1); v += __shfl_xor(v, 2);
    v += __shfl_xor(v, 4); v += __shfl_xor(v, 8);
    const float rstd = 1.0f / sqrtf(v * (1.f / 256.f) + 1e-5f);

    float n[16];
    #pragma unroll
    for (int j = 0; j < 16; ++j)
        n[j] = fmaf((pr[j] - mu) * rstd, lnw[j], lnb[j]);

    float p[16];
    #pragma unroll
    for (int e = 0; e < 16; ++e) p[e] = 0.f;
    #pragma unroll
    for (int j = 0; j < 16; ++j) {
        const float nv = n[j];
        const int  h   = ptx + 16 * j;
        #pragma unroll
        for (int e = 0; e < 16; ++e)
            p[e] = fmaf(nv, smem[WG_OFF + e * H + h], p[e]);
    }
    #pragma unroll
    for (int m = 1; m < 16; m <<= 1)
        #pragma unroll
        for (int e = 0; e < 16; ++e) p[e] += __shfl_xor(p[e], m);
    #pragma unroll
    for (int e = 0; e < 16; ++e) p[e] = p[e] / temp;

    float myz = 0.f;
    if (ptx == 0) {
        #pragma unroll
        for (int e = 0; e < 16; ++e) myz = fmaf(p[e], p[e], myz);
    }

    // softmax (stable)
    float mx = p[0];
    #pragma unroll
    for (int e = 1; e < 16; ++e) mx = fmaxf(mx, p[e]);
    float w[16]; float sw = 0.f;
    #pragma unroll
    for (int e = 0; e < 16; ++e) { w[e] = expf(p[e] - mx); sw += w[e]; }
    #pragma unroll
    for (int e = 0; e < 16; ++e) w[e] = w[e] / sw;

    // top-2 (ties -> lower index)
    float w1 = -1.f; int i1 = 0; float w2 = -1.f; int i2 = 0;
    #pragma unroll
    for (int e = 0; e < 16; ++e) {
        const float we = w[e];
        if (we > w1)      { w2 = w1; i2 = i1; w1 = we; i1 = e; }
        else if (we > w2) { w2 = we; i2 = e; }
    }
    const float rs = 1.f / (w1 + w2 + 1e-6f);
    out_rw  [(size_t)tok * E + ptx] = w[ptx];
    out_disp[(size_t)tok * E + ptx] = (ptx == i1) ? w1 * rs : (ptx == i2 ? w2 * rs : 0.f);

    // ---- loss partials: in-wave reduce 4 tokens, then LDS atomics ----
    float mylb = w[ptx];
    mylb += __shfl_xor(mylb, 16); mylb += __shfl_xor(mylb, 32);
    myz  += __shfl_xor(myz, 16);  myz  += __shfl_xor(myz, 32);
    if ((t & 63) < 16) atomicAdd(&smem[LB_OFF + ptx], mylb);
    if ((t & 63) == 0) atomicAdd(&smem[Z_OFF], myz);
    __syncthreads();
    if (t < 16)  ws_part[blockIdx.x * WS_STRIDE + t]  = smem[LB_OFF + t];
    if (t == 16) ws_part[blockIdx.x * WS_STRIDE + 16] = smem[Z_OFF];
}

__global__ void router_final(const float* __restrict__ ws_part,
                             float* __restrict__ out_loss, int nblocks, int T)
{
    const int l = threadIdx.x;   // 64 threads
    float lb[16]; float z = 0.f;
    #pragma unroll
    for (int e = 0; e < 16; ++e) lb[e] = 0.f;
    for (int b = l; b < nblocks; b += 64) {
        #pragma unroll
        for (int e = 0; e < 16; ++e) lb[e] += ws_part[b * WS_STRIDE + e];
        z += ws_part[b * WS_STRIDE + 16];
    }
    #pragma unroll
    for (int m = 1; m < 64; m <<= 1) {
        #pragma unroll
        for (int e = 0; e < 16; ++e) lb[e] += __shfl_xor(lb[e], m);
        z += __shfl_xor(z, m);
    }
    if (l == 0) {
        const float zloss = z / (float)(T * 16);
        const float ideal = 1.f / 16.f;
        float lbl = 0.f;
        #pragma unroll
        for (int e = 0; e < 16; ++e) {
            const float a = lb[e] / (float)T;
            lbl += ideal * (logf(ideal) - logf(a));
        }
        lbl *= (1.f / 16.f);
        out_loss[0] = 0.005f * zloss + 0.005f * lbl;
    }
}

extern "C" void kernel_launch(void* const* d_in, const int* in_sizes, int n_in,
                              void* d_out, int out_size, void* d_ws, size_t ws_size,
                              hipStream_t stream)
{
    const float* x    = (const float*)d_in[0];
    const float* Wp   = (const float*)d_in[1];
    const float* Wg   = (const float*)d_in[2];
    const float* lnw  = (const float*)d_in[3];
    const float* lnb  = (const float*)d_in[4];
    const float* temp = (const float*)d_in[5];
    const int T = in_sizes[0] / D;           // 16384
    float* out      = (float*)d_out;
    float* out_rw   = out;
    float* out_disp = out + (size_t)T * E;
    float* out_loss = out + (size_t)2 * T * E;
    float* ws_part  = (float*)d_ws;
    const int nblocks = T / TMB;             // 1024

    hipLaunchKernelGGL(router_main, dim3(nblocks), dim3(THREADS), 0, stream,
                       x, Wp, Wg, lnw, lnb, temp, out_rw, out_disp, ws_part);
    hipLaunchKernelGGL(router_final, dim3(1), dim3(64), 0, stream,
                       ws_part, out_loss, nblocks, T);
}

// Round 14
// 418.211 us; speedup vs baseline: 1.5425x; 1.4469x over previous
//
#include <hip/hip_runtime.h>
#include <hip/hip_bf16.h>
#include <math.h>

#define D 2048
#define H 256
#define E 16
#define TMB 16                 // tokens per block
#define BK 16                  // k-chunk; each ku-lane owns a 4-k window
#define NCH (D / BK)           // 128
#define LDK 20                 // Wp LDS row stride (floats): (5tx+ku)&7 uniform bank slots
// double-buffered staging
#define WP0_OFF 0              // [256][20] = 5120
#define WP1_OFF 5120
#define X0_OFF  10240          // [16][16] = 256
#define X1_OFF  10496          // staging ends 10752
// post-phase aliases (staging dead). Proj rows have 256 columns -> stride MUST be >=256.
#define SB_LDW 257             // R13 bug: 254 < 256 corrupted 2 cols/row. 257 = proven (R11/R12).
#define SB_OFF 0               // [16][257] = 4112
#define WG_OFF 4112            // [16][256] = 4096 -> 8208
#define LB_OFF 8208
#define Z_OFF  8224
#define SMEM_FLOATS 10752      // 43.0 KB
#define THREADS 256
#define WS_STRIDE 20

// Occupancy model distilled from R2..R12: waves/SIMD = floor(256 / VGPR).
// acc[8][8] demand ~110 regs => spill-free max is 2 waves/SIMD (cap 128).
// Bare bounds lets the allocator CHOOSE 3/SIMD with voluntary spill (R12: 76 regs
// + 292MB scratch). waves_per_eu(2,2) pins the 128-reg regime: no spill, 2/SIMD.
__global__ __launch_bounds__(THREADS)
__attribute__((amdgpu_waves_per_eu(2, 2)))
void router_main(const float* __restrict__ x, const float* __restrict__ Wp,
                 const float* __restrict__ Wg, const float* __restrict__ lnw_g,
                 const float* __restrict__ lnb_g, const float* __restrict__ temp_g,
                 float* __restrict__ out_rw, float* __restrict__ out_disp,
                 float* __restrict__ ws_part)
{
    __shared__ __align__(16) float smem[SMEM_FLOATS];
    const int t  = threadIdx.x;
    const int tx = t & 15;           // h-lane (lane bits 0-3)
    const int ku = (t >> 4) & 3;     // private 4-k window (lane bits 4-5)
    const int wv = t >> 6;           // wave 0..3
    const int tb = wv & 1;           // token octet
    const int hb = wv >> 1;          // h-half
    const int srow = t >> 2;         // staging row unit 0..63
    const int scol = (t & 3) << 2;   // staging col (floats)
    const int tok0 = blockIdx.x * TMB;

    float acc[8][8];
    #pragma unroll
    for (int i = 0; i < 8; ++i)
        #pragma unroll
        for (int j = 0; j < 8; ++j) acc[i][j] = 0.f;

    float4 wst[4], xst;
    auto ISSUE = [&](int k0) {
        #pragma unroll
        for (int p = 0; p < 4; ++p)
            wst[p] = *(const float4*)&Wp[(size_t)(p * 64 + srow) * D + k0 + scol];
        if (t < 64) xst = *(const float4*)&x[(size_t)(tok0 + srow) * D + k0 + scol];
    };
    auto WRITE = [&](int buf) {
        const int wpo = buf ? WP1_OFF : WP0_OFF;
        const int xo  = buf ? X1_OFF  : X0_OFF;
        #pragma unroll
        for (int p = 0; p < 4; ++p)
            *(float4*)&smem[wpo + (p * 64 + srow) * LDK + scol] = wst[p];
        if (t < 64) *(float4*)&smem[xo + srow * 16 + scol] = xst;
    };

    ISSUE(0);
    WRITE(0);
    __syncthreads();

    for (int c = 0; c < NCH; ++c) {
        const int buf = c & 1;
        if (c + 1 < NCH) ISSUE((c + 1) * BK);   // global latency hides under compute

        const float* wbase = &smem[(buf ? WP1_OFF : WP0_OFF) + (hb * 128 + tx) * LDK + ku * 4];
        const float* xbase = &smem[(buf ? X1_OFF : X0_OFF) + tb * 128 + ku * 4];

        float4 xa[8];
        #pragma unroll
        for (int i = 0; i < 8; ++i)
            xa[i] = *(const float4*)&xbase[i * 16];          // 16-way broadcast reads
        #pragma unroll
        for (int j = 0; j < 8; ++j) {
            const float4 wvv = *(const float4*)&wbase[j * 16 * LDK];  // 64-distinct b128
            #pragma unroll
            for (int i = 0; i < 8; ++i) {
                acc[i][j] = fmaf(xa[i].x, wvv.x, acc[i][j]);
                acc[i][j] = fmaf(xa[i].y, wvv.y, acc[i][j]);
                acc[i][j] = fmaf(xa[i].z, wvv.z, acc[i][j]);
                acc[i][j] = fmaf(xa[i].w, wvv.w, acc[i][j]);
            }
        }
        if (c + 1 < NCH) WRITE(1 - buf);        // into the buffer not being read
        __syncthreads();                         // one barrier per chunk (dbuf)
    }

    // ---- k-window reduction: in-wave butterflies over lane bits 4,5 ----
    #pragma unroll
    for (int i = 0; i < 8; ++i)
        #pragma unroll
        for (int j = 0; j < 8; ++j) {
            acc[i][j] += __shfl_xor(acc[i][j], 16);
            acc[i][j] += __shfl_xor(acc[i][j], 32);
        }

    __syncthreads();                             // staging region now dead

    // ---- dump proj into SB [16][257]; stage Wg; zero reducers ----
    if (ku == 0) {
        #pragma unroll
        for (int i = 0; i < 8; ++i)
            #pragma unroll
            for (int j = 0; j < 8; ++j)
                smem[SB_OFF + (tb * 8 + i) * SB_LDW + hb * 128 + tx + 16 * j] = acc[i][j];
    }
    #pragma unroll
    for (int p = 0; p < 4; ++p)
        *(float4*)&smem[WG_OFF + (p * 256 + t) * 4] = *(const float4*)&Wg[(p * 256 + t) * 4];
    if (t < 16)  smem[LB_OFF + t] = 0.f;
    if (t == 16) smem[Z_OFF] = 0.f;
    __syncthreads();

    // ---- post phase: one token per 16-thread slot ----
    const int ptx  = t & 15;
    const int tokl = t >> 4;                  // 0..15
    const int tok  = tok0 + tokl;
    const float temp = fabsf(temp_g[0]) + 1e-6f;

    float lnw[16], lnb[16];
    #pragma unroll
    for (int j = 0; j < 16; ++j) {
        lnw[j] = lnw_g[ptx + 16 * j];
        lnb[j] = lnb_g[ptx + 16 * j];
    }

    float pr[16];
    #pragma unroll
    for (int j = 0; j < 16; ++j)
        pr[j] = smem[SB_OFF + tokl * SB_LDW + ptx + 16 * j];

    // mean / variance over H (16-lane butterfly)
    float s = 0.f;
    #pragma unroll
    for (int j = 0; j < 16; ++j) s += pr[j];
    s += __shfl_xor(s, 1); s += __shfl_xor(s, 2);
    s += __shfl_xor(s, 4); s += __shfl_xor(s, 8);
    const float mu = s * (1.f / 256.f);
    float v = 0.f;
    #pragma unroll
    for (int j = 0; j < 16; ++j) { const float d = pr[j] - mu; v = fmaf(d, d, v); }
    v += __shfl_xor(v, 1); v += __shfl_xor(v, 2);
    v += __shfl_xor(v, 4); v += __shfl_xor(v, 8);
    const float rstd = 1.0f / sqrtf(v * (1.f / 256.f) + 1e-5f);

    float n[16];
    #pragma unroll
    for (int j = 0; j < 16; ++j)
        n[j] = fmaf((pr[j] - mu) * rstd, lnw[j], lnb[j]);

    float p[16];
    #pragma unroll
    for (int e = 0; e < 16; ++e) p[e] = 0.f;
    #pragma unroll
    for (int j = 0; j < 16; ++j) {
        const float nv = n[j];
        const int  h   = ptx + 16 * j;
        #pragma unroll
        for (int e = 0; e < 16; ++e)
            p[e] = fmaf(nv, smem[WG_OFF + e * H + h], p[e]);
    }
    #pragma unroll
    for (int m = 1; m < 16; m <<= 1)
        #pragma unroll
        for (int e = 0; e < 16; ++e) p[e] += __shfl_xor(p[e], m);
    #pragma unroll
    for (int e = 0; e < 16; ++e) p[e] = p[e] / temp;

    float myz = 0.f;
    if (ptx == 0) {
        #pragma unroll
        for (int e = 0; e < 16; ++e) myz = fmaf(p[e], p[e], myz);
    }

    // softmax (stable)
    float mx = p[0];
    #pragma unroll
    for (int e = 1; e < 16; ++e) mx = fmaxf(mx, p[e]);
    float w[16]; float sw = 0.f;
    #pragma unroll
    for (int e = 0; e < 16; ++e) { w[e] = expf(p[e] - mx); sw += w[e]; }
    #pragma unroll
    for (int e = 0; e < 16; ++e) w[e] = w[e] / sw;

    // top-2 (ties -> lower index)
    float w1 = -1.f; int i1 = 0; float w2 = -1.f; int i2 = 0;
    #pragma unroll
    for (int e = 0; e < 16; ++e) {
        const float we = w[e];
        if (we > w1)      { w2 = w1; i2 = i1; w1 = we; i1 = e; }
        else if (we > w2) { w2 = we; i2 = e; }
    }
    const float rs = 1.f / (w1 + w2 + 1e-6f);
    out_rw  [(size_t)tok * E + ptx] = w[ptx];
    out_disp[(size_t)tok * E + ptx] = (ptx == i1) ? w1 * rs : (ptx == i2 ? w2 * rs : 0.f);

    // ---- loss partials: in-wave reduce 4 tokens, then LDS atomics ----
    float mylb = w[ptx];
    mylb += __shfl_xor(mylb, 16); mylb += __shfl_xor(mylb, 32);
    myz  += __shfl_xor(myz, 16);  myz  += __shfl_xor(myz, 32);
    if ((t & 63) < 16) atomicAdd(&smem[LB_OFF + ptx], mylb);
    if ((t & 63) == 0) atomicAdd(&smem[Z_OFF], myz);
    __syncthreads();
    if (t < 16)  ws_part[blockIdx.x * WS_STRIDE + t]  = smem[LB_OFF + t];
    if (t == 16) ws_part[blockIdx.x * WS_STRIDE + 16] = smem[Z_OFF];
}

__global__ void router_final(const float* __restrict__ ws_part,
                             float* __restrict__ out_loss, int nblocks, int T)
{
    const int l = threadIdx.x;   // 64 threads
    float lb[16]; float z = 0.f;
    #pragma unroll
    for (int e = 0; e < 16; ++e) lb[e] = 0.f;
    for (int b = l; b < nblocks; b += 64) {
        #pragma unroll
        for (int e = 0; e < 16; ++e) lb[e] += ws_part[b * WS_STRIDE + e];
        z += ws_part[b * WS_STRIDE + 16];
    }
    #pragma unroll
    for (int m = 1; m < 64; m <<= 1) {
        #pragma unroll
        for (int e = 0; e < 16; ++e) lb[e] += __shfl_xor(lb[e], m);
        z += __shfl_xor(z, m);
    }
    if (l == 0) {
        const float zloss = z / (float)(T * 16);
        const float ideal = 1.f / 16.f;
        float lbl = 0.f;
        #pragma unroll
        for (int e = 0; e < 16; ++e) {
            const float a = lb[e] / (float)T;
            lbl += ideal * (logf(ideal) - logf(a));
        }
        lbl *= (1.f / 16.f);
        out_loss[0] = 0.005f * zloss + 0.005f * lbl;
    }
}

extern "C" void kernel_launch(void* const* d_in, const int* in_sizes, int n_in,
                              void* d_out, int out_size, void* d_ws, size_t ws_size,
                              hipStream_t stream)
{
    const float* x    = (const float*)d_in[0];
    const float* Wp   = (const float*)d_in[1];
    const float* Wg   = (const float*)d_in[2];
    const float* lnw  = (const float*)d_in[3];
    const float* lnb  = (const float*)d_in[4];
    const float* temp = (const float*)d_in[5];
    const int T = in_sizes[0] / D;           // 16384
    float* out      = (float*)d_out;
    float* out_rw   = out;
    float* out_disp = out + (size_t)T * E;
    float* out_loss = out + (size_t)2 * T * E;
    float* ws_part  = (float*)d_ws;
    const int nblocks = T / TMB;             // 1024

    hipLaunchKernelGGL(router_main, dim3(nblocks), dim3(THREADS), 0, stream,
                       x, Wp, Wg, lnw, lnb, temp, out_rw, out_disp, ws_part);
    hipLaunchKernelGGL(router_final, dim3(1), dim3(64), 0, stream,
                       ws_part, out_loss, nblocks, T);
}